// Round 6
// baseline (1100.066 us; speedup 1.0000x reference)
//
#include <hip/hip_runtime.h>
#include <cstdint>

#define N_NODES 50000
#define N_EDGES 800000
#define IN_DIM  256
#define HID     128
#define T_STEPS 8

// ---------- float <-> orderable uint encoding for atomic min/max ----------
static __device__ __forceinline__ unsigned int enc_f(float f) {
    unsigned int u = __float_as_uint(f);
    return (u & 0x80000000u) ? ~u : (u | 0x80000000u);
}
static __device__ __forceinline__ float dec_f(unsigned int u) {
    unsigned int b = (u & 0x80000000u) ? (u ^ 0x80000000u) : ~u;
    return __uint_as_float(b);
}

// ---------- CSR build ----------
__global__ void k_count(const int* __restrict__ dst, int* __restrict__ counts) {
    int e = blockIdx.x * blockDim.x + threadIdx.x;
    if (e < N_EDGES) atomicAdd(&counts[dst[e]], 1);
}

__global__ void k_scan1(const int* __restrict__ counts, int* __restrict__ row_tmp,
                        int* __restrict__ blocksum) {
    __shared__ int sh[256];
    int t = threadIdx.x, i = blockIdx.x * 256 + t;
    int c = (i < N_NODES) ? counts[i] : 0;
    sh[t] = c; __syncthreads();
    for (int off = 1; off < 256; off <<= 1) {
        int val = (t >= off) ? sh[t - off] : 0;
        __syncthreads();
        sh[t] += val;
        __syncthreads();
    }
    if (i < N_NODES) row_tmp[i] = sh[t] - c;     // exclusive
    if (t == 255) blocksum[blockIdx.x] = sh[255];
}

__global__ void k_scan2(const int* __restrict__ blocksum, int* __restrict__ blockoff,
                        int nb, int* __restrict__ row_ptr) {
    if (threadIdx.x == 0) {
        int acc = 0;
        for (int b = 0; b < nb; ++b) { blockoff[b] = acc; acc += blocksum[b]; }
        row_ptr[N_NODES] = acc;   // == N_EDGES
    }
}

__global__ void k_scan3(const int* __restrict__ row_tmp, const int* __restrict__ blockoff,
                        int* __restrict__ row_ptr) {
    int i = blockIdx.x * blockDim.x + threadIdx.x;
    if (i < N_NODES) row_ptr[i] = row_tmp[i] + blockoff[i >> 8];
}

// fill CSR slots directly with the (eid, src, attr) triple (arbitrary order)
__global__ void k_fill(const int* __restrict__ dst, const int* __restrict__ src,
                       const float* __restrict__ attr,
                       const int* __restrict__ row_ptr, int* __restrict__ cursor,
                       int* __restrict__ eid, int* __restrict__ src_s,
                       float* __restrict__ attr_s) {
    int e = blockIdx.x * blockDim.x + threadIdx.x;
    if (e >= N_EDGES) return;
    int d = dst[e];
    int p = row_ptr[d] + atomicAdd(&cursor[d], 1);
    eid[p]    = e;
    src_s[p]  = src[e];
    attr_s[p] = attr[e];
}

// wave-wide bitonic sort per node by eid: restores np.add.at ascending order
__global__ __launch_bounds__(256) void k_bsort(const int* __restrict__ row_ptr,
                                               int* __restrict__ eid,
                                               int* __restrict__ src_s,
                                               float* __restrict__ attr_s) {
    int node = blockIdx.x * 4 + (threadIdx.x >> 6);
    int l = threadIdx.x & 63;
    int beg = row_ptr[node], end = row_ptr[node + 1], cnt = end - beg;
    if (cnt <= 1) return;
    if (cnt <= 64) {
        int key = 0x7FFFFFFF, sv = 0; float av = 0.f;
        if (l < cnt) { key = eid[beg + l]; sv = src_s[beg + l]; av = attr_s[beg + l]; }
        #pragma unroll
        for (int k = 2; k <= 64; k <<= 1) {
            for (int j = k >> 1; j > 0; j >>= 1) {
                int   pk = __shfl_xor(key, j);
                int   ps = __shfl_xor(sv, j);
                float pa = __shfl_xor(av, j);
                bool lower = (l & j) == 0;
                bool asc   = (l & k) == 0;
                bool take_min = (lower == asc);
                bool take = take_min ? (pk < key) : (pk > key);
                if (take) { key = pk; sv = ps; av = pa; }
            }
        }
        if (l < cnt) { eid[beg + l] = key; src_s[beg + l] = sv; attr_s[beg + l] = av; }
    } else if (l == 0) {
        for (int i = beg + 1; i < end; ++i) {
            int ke = eid[i]; int ks = src_s[i]; float ka = attr_s[i];
            int m = i - 1;
            while (m >= beg && eid[m] > ke) {
                eid[m+1] = eid[m]; src_s[m+1] = src_s[m]; attr_s[m+1] = attr_s[m]; --m;
            }
            eid[m+1] = ke; src_s[m+1] = ks; attr_s[m+1] = ka;
        }
    }
}

// ---------- tiled GEMM: 64 nodes x 128 feats per block, fused min/max ----------
__global__ __launch_bounds__(256) void k_gemm(const float* __restrict__ x,
                                              const float* __restrict__ W,
                                              const float* __restrict__ b,
                                              float* __restrict__ h,
                                              unsigned int* __restrict__ mn_e,
                                              unsigned int* __restrict__ mx_e) {
    __shared__ float Ws[32 * 128];
    __shared__ float xs[64 * 36];
    __shared__ float red_mn[8 * 128];
    __shared__ float red_mx[8 * 128];
    const int tid = threadIdx.x;
    const int n0 = blockIdx.x * 64;
    const int jt = tid & 31, nt = tid >> 5;
    const int j0 = jt * 4;

    float acc[8][4];
    #pragma unroll
    for (int a = 0; a < 8; ++a)
        #pragma unroll
        for (int c = 0; c < 4; ++c) acc[a][c] = 0.0f;

    const int ldn = tid >> 2;
    const int kq  = (tid & 3) * 8;
    const int xrow = (n0 + ldn < N_NODES) ? (n0 + ldn) : (N_NODES - 1);
    const float* xg = x + (size_t)xrow * IN_DIM;

    for (int kc = 0; kc < IN_DIM; kc += 32) {
        __syncthreads();
        float4 xa = *(const float4*)(xg + kc + kq);
        float4 xb = *(const float4*)(xg + kc + kq + 4);
        *(float4*)&xs[ldn * 36 + kq]     = xa;
        *(float4*)&xs[ldn * 36 + kq + 4] = xb;
        #pragma unroll
        for (int p = 0; p < 4; ++p) {
            int r = nt + p * 8;
            *(float4*)&Ws[r * 128 + j0] =
                *(const float4*)(W + (size_t)(kc + r) * HID + j0);
        }
        __syncthreads();
        const float* xbase = &xs[nt * 8 * 36];
        #pragma unroll 4
        for (int k = 0; k < 32; ++k) {
            float4 wf = *(const float4*)&Ws[k * 128 + j0];
            #pragma unroll
            for (int ni = 0; ni < 8; ++ni) {
                float xv = xbase[ni * 36 + k];
                acc[ni][0] = __fmaf_rn(xv, wf.x, acc[ni][0]);
                acc[ni][1] = __fmaf_rn(xv, wf.y, acc[ni][1]);
                acc[ni][2] = __fmaf_rn(xv, wf.z, acc[ni][2]);
                acc[ni][3] = __fmaf_rn(xv, wf.w, acc[ni][3]);
            }
        }
    }

    float4 bv = *(const float4*)(b + j0);
    float lmn[4], lmx[4];
    #pragma unroll
    for (int c = 0; c < 4; ++c) { lmn[c] = INFINITY; lmx[c] = -INFINITY; }
    #pragma unroll
    for (int ni = 0; ni < 8; ++ni) {
        acc[ni][0] = __fadd_rn(acc[ni][0], bv.x);
        acc[ni][1] = __fadd_rn(acc[ni][1], bv.y);
        acc[ni][2] = __fadd_rn(acc[ni][2], bv.z);
        acc[ni][3] = __fadd_rn(acc[ni][3], bv.w);
        #pragma unroll
        for (int c = 0; c < 4; ++c) {
            lmn[c] = fminf(lmn[c], acc[ni][c]);
            lmx[c] = fmaxf(lmx[c], acc[ni][c]);
        }
    }
    #pragma unroll
    for (int c = 0; c < 4; ++c) {
        red_mn[nt * 128 + j0 + c] = lmn[c];
        red_mx[nt * 128 + j0 + c] = lmx[c];
    }
    __syncthreads();
    if (tid < 128) {
        float mnv = red_mn[tid], mxv = red_mx[tid];
        #pragma unroll
        for (int r = 1; r < 8; ++r) {
            mnv = fminf(mnv, red_mn[r * 128 + tid]);
            mxv = fmaxf(mxv, red_mx[r * 128 + tid]);
        }
        atomicMin(&mn_e[tid], enc_f(mnv));
        atomicMax(&mx_e[tid], enc_f(mxv));
    }
    #pragma unroll
    for (int ni = 0; ni < 8; ++ni) {
        int n = n0 + nt * 8 + ni;
        if (n < N_NODES)
            *(float4*)&h[(size_t)n * HID + j0] =
                make_float4(acc[ni][0], acc[ni][1], acc[ni][2], acc[ni][3]);
    }
}

// ---------- init spike bitmask ----------
__global__ void k_init_bits(const int* __restrict__ spike_node, uint32_t* __restrict__ sb) {
    int n = blockIdx.x * blockDim.x + threadIdx.x;
    if (n >= N_NODES) return;
    uint32_t f = spike_node[n] ? 0xFFFFFFFFu : 0u;
    sb[(size_t)n * 4 + 0] = f;
    sb[(size_t)n * 4 + 1] = f;
    sb[(size_t)n * 4 + 2] = f;
    sb[(size_t)n * 4 + 3] = f;
}

// ---------- device-wide generation barrier (persistent kernel, plain launch) ----------
static __device__ __forceinline__ void gbar(int* cnt, int* gen, int nblk) {
    __syncthreads();                       // all block stores issued (vmcnt drained)
    if (threadIdx.x == 0) {
        __threadfence();                   // release: flush this XCD's L2
        int g = __hip_atomic_load(gen, __ATOMIC_RELAXED, __HIP_MEMORY_SCOPE_AGENT);
        int arrived = __hip_atomic_fetch_add(cnt, 1, __ATOMIC_ACQ_REL,
                                             __HIP_MEMORY_SCOPE_AGENT);
        if (arrived == nblk - 1) {
            __hip_atomic_store(cnt, 0, __ATOMIC_RELAXED, __HIP_MEMORY_SCOPE_AGENT);
            __threadfence();
            __hip_atomic_fetch_add(gen, 1, __ATOMIC_ACQ_REL, __HIP_MEMORY_SCOPE_AGENT);
        } else {
            while (__hip_atomic_load(gen, __ATOMIC_RELAXED,
                                     __HIP_MEMORY_SCOPE_AGENT) == g)
                __builtin_amdgcn_s_sleep(16);
        }
        __threadfence();                   // acquire: invalidate stale L1/L2 lines
    }
    __syncthreads();
}

// ---------- persistent fused 8-step LIF (plain launch, graph-capturable) ----------
// 511 blocks x 256 threads; needs only 2 blocks/CU co-resident (512 >= 511;
// R4/R5 proved 758 blocks co-reside). h/v/ref in registers (slot loop fully
// unrolled — see R4 errata: `unroll 1` => scratch spill). Gather uses the
// R2-proven staged pattern: parallel 256-thread stage of all block edges'
// spike words into LDS, then serial LDS-broadcast accumulate (no global
// latency in the dependent chain, unlike R5's k_fused at 1740 us).
#define NPB   98
#define NSLOT 13
#define ECAP  2048
#define GRID_P ((N_NODES + NPB - 1) / NPB)   // 511
__global__ __launch_bounds__(256, 2) void k_lif(
    const int* __restrict__ row_ptr,
    const int* __restrict__ src_s,
    const float* __restrict__ attr_s,
    uint32_t* __restrict__ sbA,
    uint32_t* __restrict__ sbB,
    const float* __restrict__ h_raw,
    const unsigned int* __restrict__ mn_e,
    const unsigned int* __restrict__ mx_e,
    float* __restrict__ out,
    int* __restrict__ bar_cnt,
    int* __restrict__ bar_gen)
{
    __shared__ int      lrp[NPB + 1];
    __shared__ int      ed_src_l[ECAP];       //  8 KB
    __shared__ float    ed_attr_l[ECAP];      //  8 KB
    __shared__ uint32_t ed_wds[ECAP * 4];     // 32 KB staged spike words
    __shared__ uint32_t sbw[NPB][4];          // 1.5 KB

    const int tid = threadIdx.x;
    const int g   = tid >> 5;                 // node group 0..7
    const int ln  = tid & 31;                 // features 4ln..4ln+3
    const int n0  = blockIdx.x * NPB;
    const int ncnt = min(NPB, N_NODES - n0);  // >0 for all 511 blocks
    const int w = ln >> 3, shb = (ln & 7) * 4;
    const size_t NH = (size_t)N_NODES * HID;

    if (tid <= ncnt) lrp[tid] = row_ptr[n0 + tid];
    __syncthreads();
    const int ebase = lrp[0];
    const int etot  = lrp[ncnt] - ebase;
    const bool inlds = (etot <= ECAP);        // mean 1568, +5 sigma ~1770 < 2048
    if (inlds) {
        for (int i = tid; i < etot; i += 256) {
            ed_src_l[i]  = src_s[ebase + i];
            ed_attr_l[i] = attr_s[ebase + i];
        }
    }

    // per-lane normalization constants
    uint4 mnu = *(const uint4*)&mn_e[ln * 4];
    uint4 mxu = *(const uint4*)&mx_e[ln * 4];
    float mn0 = dec_f(mnu.x), mn1 = dec_f(mnu.y), mn2 = dec_f(mnu.z), mn3 = dec_f(mnu.w);
    float dd0 = __fadd_rn(__fsub_rn(dec_f(mxu.x), mn0), 1e-6f);
    float dd1 = __fadd_rn(__fsub_rn(dec_f(mxu.y), mn1), 1e-6f);
    float dd2 = __fadd_rn(__fsub_rn(dec_f(mxu.z), mn2), 1e-6f);
    float dd3 = __fadd_rn(__fsub_rn(dec_f(mxu.w), mn3), 1e-6f);

    // load + normalize h; init v, ref (all in registers/AGPRs; fully static)
    float4 hs[NSLOT], vs[NSLOT];
    uint32_t rcs[NSLOT];
    #pragma unroll
    for (int s = 0; s < NSLOT; ++s) {
        hs[s] = make_float4(0.f, 0.f, 0.f, 0.f);
        vs[s] = make_float4(0.f, 0.f, 0.f, 0.f);
        rcs[s] = 0u;
        int m = s * 8 + g;
        if (m < ncnt) {
            size_t idx = (size_t)(n0 + m) * HID + ln * 4;
            float4 t = *(const float4*)&h_raw[idx];
            t.x = __fdiv_rn(__fsub_rn(t.x, mn0), dd0);
            t.y = __fdiv_rn(__fsub_rn(t.y, mn1), dd1);
            t.z = __fdiv_rn(__fsub_rn(t.z, mn2), dd2);
            t.w = __fdiv_rn(__fsub_rn(t.w, mn3), dd3);
            hs[s] = t;
        }
    }
    __syncthreads();   // ed_src_l/ed_attr_l staged before first use

    for (int t = 0; t < T_STEPS; ++t) {
        const uint32_t* cur = (t & 1) ? sbB : sbA;
        uint32_t*       nxt = (t & 1) ? sbA : sbB;
        if (t > 0) gbar(bar_cnt, bar_gen, GRID_P);   // masks of step t-1 visible

        // zero next-mask accumulator + stage this step's spike words into LDS
        for (int i = tid; i < ncnt * 4; i += 256) ((uint32_t*)sbw)[i] = 0u;
        if (inlds) {
            for (int i = tid; i < etot; i += 256) {
                int s = ed_src_l[i];
                *(uint4*)&ed_wds[i * 4] = *(const uint4*)&cur[(size_t)s * 4];
            }
        }
        __syncthreads();

        #pragma unroll
        for (int s = 0; s < NSLOT; ++s) {
            int m = s * 8 + g;
            if (m < ncnt) {
                float ag0 = 0.f, ag1 = 0.f, ag2 = 0.f, ag3 = 0.f;
                if (inlds) {
                    int lb = lrp[m] - ebase, le = lrp[m + 1] - ebase;
                    for (int i = lb; i < le; ++i) {      // ascending edge order
                        uint32_t u = ed_wds[i * 4 + w];  // LDS broadcast
                        float a = ed_attr_l[i];
                        uint32_t bits = (u >> shb) & 0xFu;
                        ag0 = __fadd_rn(ag0, (bits & 1u) ? a : 0.f);  // +0.0 exact
                        ag1 = __fadd_rn(ag1, (bits & 2u) ? a : 0.f);
                        ag2 = __fadd_rn(ag2, (bits & 4u) ? a : 0.f);
                        ag3 = __fadd_rn(ag3, (bits & 8u) ? a : 0.f);
                    }
                } else {                                 // overflow fallback
                    int lb = lrp[m], le = lrp[m + 1];
                    for (int i = lb; i < le; ++i) {
                        uint32_t u = cur[(size_t)src_s[i] * 4 + w];
                        float a = attr_s[i];
                        uint32_t bits = (u >> shb) & 0xFu;
                        ag0 = __fadd_rn(ag0, (bits & 1u) ? a : 0.f);
                        ag1 = __fadd_rn(ag1, (bits & 2u) ? a : 0.f);
                        ag2 = __fadd_rn(ag2, (bits & 4u) ? a : 0.f);
                        ag3 = __fadd_rn(ag3, (bits & 8u) ? a : 0.f);
                    }
                }

                // LIF update (identical FP sequence to reference)
                float hv[4] = {hs[s].x, hs[s].y, hs[s].z, hs[s].w};
                float vv[4] = {vs[s].x, vs[s].y, vs[s].z, vs[s].w};
                float ag[4] = {ag0, ag1, ag2, ag3};
                float vf[4], sf[4];
                uint32_t rcu = rcs[s], rcn = 0u, nib = 0u;
                #pragma unroll
                for (int q = 0; q < 4; ++q) {
                    float vn = __fadd_rn(__fadd_rn(__fmul_rn(0.8f, vv[q]), hv[q]), ag[q]);
                    uint32_t rc = (rcu >> (8 * q)) & 0xFFu;
                    bool spk = (vn >= 0.5f) && (rc == 0u);
                    vf[q] = spk ? 0.0f : vn;
                    sf[q] = spk ? 1.0f : 0.0f;
                    uint32_t rnew = spk ? 2u : (rc > 0u ? rc - 1u : 0u);
                    rcn |= rnew << (8 * q);
                    nib |= (spk ? 1u : 0u) << q;
                }
                vs[s] = make_float4(vf[0], vf[1], vf[2], vf[3]);
                rcs[s] = rcn;
                size_t idx = (size_t)(n0 + m) * HID + ln * 4;
                *(float4*)&out[NH + (size_t)t * NH + idx] =
                    make_float4(sf[0], sf[1], sf[2], sf[3]);
                if (t == T_STEPS - 1) {
                    *(float4*)&out[idx] = make_float4(
                        __fadd_rn(hv[0], __fmul_rn(0.5f, vf[0])),
                        __fadd_rn(hv[1], __fmul_rn(0.5f, vf[1])),
                        __fadd_rn(hv[2], __fmul_rn(0.5f, vf[2])),
                        __fadd_rn(hv[3], __fmul_rn(0.5f, vf[3])));
                }
                atomicOr(&sbw[m][w], nib << shb);
            }
        }
        __syncthreads();
        for (int i = tid; i < ncnt * 4; i += 256)
            nxt[(size_t)n0 * 4 + i] = ((uint32_t*)sbw)[i];
    }
}

extern "C" void kernel_launch(void* const* d_in, const int* in_sizes, int n_in,
                              void* d_out, int out_size, void* d_ws, size_t ws_size,
                              hipStream_t stream) {
    const float* x          = (const float*)d_in[0];
    const int*   spike_node = (const int*)  d_in[1];
    const int*   edge_index = (const int*)  d_in[2];   // [2][E]
    const float* edge_attr  = (const float*)d_in[4];
    const float* W          = (const float*)d_in[5];
    const float* b          = (const float*)d_in[6];
    float* out = (float*)d_out;

    const int* src = edge_index;
    const int* dst = edge_index + N_EDGES;

    char* wsp = (char*)d_ws;
    auto alloc = [&](size_t bytes) {
        char* p = wsp;
        wsp += (bytes + 255) & ~(size_t)255;
        return p;
    };
    float*         h        = (float*)        alloc((size_t)N_NODES * HID * 4);
    uint32_t*      sbA      = (uint32_t*)     alloc((size_t)N_NODES * 16);
    uint32_t*      sbB      = (uint32_t*)     alloc((size_t)N_NODES * 16);
    int*           counts   = (int*)          alloc((size_t)N_NODES * 4);
    int*           cursor   = (int*)          alloc((size_t)N_NODES * 4);
    int*           row_tmp  = (int*)          alloc((size_t)N_NODES * 4);
    int*           row_ptr  = (int*)          alloc((size_t)(N_NODES + 1) * 4);
    int*           blocksum = (int*)          alloc(256 * 4);
    int*           blockoff = (int*)          alloc(256 * 4);
    int*           eid      = (int*)          alloc((size_t)N_EDGES * 4);
    int*           src_s    = (int*)          alloc((size_t)N_EDGES * 4);
    float*         attr_s   = (float*)        alloc((size_t)N_EDGES * 4);
    unsigned int*  mn_e     = (unsigned int*) alloc(HID * 4);
    unsigned int*  mx_e     = (unsigned int*) alloc(HID * 4);
    int*           barv     = (int*)          alloc(256);   // [0]=cnt, [1]=gen

    hipMemsetAsync(counts, 0x00, (size_t)N_NODES * 4, stream);
    hipMemsetAsync(cursor, 0x00, (size_t)N_NODES * 4, stream);
    hipMemsetAsync(mn_e,   0xFF, HID * 4, stream);
    hipMemsetAsync(mx_e,   0x00, HID * 4, stream);
    hipMemsetAsync(barv,   0x00, 256, stream);

    const int NB = (N_NODES + 255) / 256;   // 196
    const int EB = (N_EDGES + 255) / 256;

    k_count<<<EB, 256, 0, stream>>>(dst, counts);
    k_scan1<<<NB, 256, 0, stream>>>(counts, row_tmp, blocksum);
    k_scan2<<<1, 64, 0, stream>>>(blocksum, blockoff, NB, row_ptr);
    k_scan3<<<NB, 256, 0, stream>>>(row_tmp, blockoff, row_ptr);
    k_fill<<<EB, 256, 0, stream>>>(dst, src, edge_attr, row_ptr, cursor, eid, src_s, attr_s);
    k_bsort<<<N_NODES / 4, 256, 0, stream>>>(row_ptr, eid, src_s, attr_s);

    k_gemm<<<(N_NODES + 63) / 64, 256, 0, stream>>>(x, W, b, h, mn_e, mx_e);
    k_init_bits<<<NB, 256, 0, stream>>>(spike_node, sbA);

    k_lif<<<GRID_P, 256, 0, stream>>>(row_ptr, src_s, attr_s, sbA, sbB,
                                      h, mn_e, mx_e, out, &barv[0], &barv[1]);
}

// Round 7
// 624.688 us; speedup vs baseline: 1.7610x; 1.7610x over previous
//
#include <hip/hip_runtime.h>
#include <cstdint>

#define N_NODES 50000
#define N_EDGES 800000
#define IN_DIM  256
#define HID     128
#define T_STEPS 8

// ---------- float <-> orderable uint encoding for atomic min/max ----------
static __device__ __forceinline__ unsigned int enc_f(float f) {
    unsigned int u = __float_as_uint(f);
    return (u & 0x80000000u) ? ~u : (u | 0x80000000u);
}
static __device__ __forceinline__ float dec_f(unsigned int u) {
    unsigned int b = (u & 0x80000000u) ? (u ^ 0x80000000u) : ~u;
    return __uint_as_float(b);
}

// ---------- CSR build ----------
__global__ void k_count(const int* __restrict__ dst, int* __restrict__ counts) {
    int e = blockIdx.x * blockDim.x + threadIdx.x;
    if (e < N_EDGES) atomicAdd(&counts[dst[e]], 1);
}

__global__ void k_scan1(const int* __restrict__ counts, int* __restrict__ row_tmp,
                        int* __restrict__ blocksum) {
    __shared__ int sh[256];
    int t = threadIdx.x, i = blockIdx.x * 256 + t;
    int c = (i < N_NODES) ? counts[i] : 0;
    sh[t] = c; __syncthreads();
    for (int off = 1; off < 256; off <<= 1) {
        int val = (t >= off) ? sh[t - off] : 0;
        __syncthreads();
        sh[t] += val;
        __syncthreads();
    }
    if (i < N_NODES) row_tmp[i] = sh[t] - c;     // exclusive
    if (t == 255) blocksum[blockIdx.x] = sh[255];
}

__global__ void k_scan2(const int* __restrict__ blocksum, int* __restrict__ blockoff,
                        int nb, int* __restrict__ row_ptr) {
    if (threadIdx.x == 0) {
        int acc = 0;
        for (int b = 0; b < nb; ++b) { blockoff[b] = acc; acc += blocksum[b]; }
        row_ptr[N_NODES] = acc;   // == N_EDGES
    }
}

__global__ void k_scan3(const int* __restrict__ row_tmp, const int* __restrict__ blockoff,
                        int* __restrict__ row_ptr) {
    int i = blockIdx.x * blockDim.x + threadIdx.x;
    if (i < N_NODES) row_ptr[i] = row_tmp[i] + blockoff[i >> 8];
}

// fill CSR slots: eid (4B) + merged (src, attr) int2 (8B) — 2 scatters/edge
__global__ void k_fill(const int* __restrict__ dst, const int* __restrict__ src,
                       const float* __restrict__ attr,
                       const int* __restrict__ row_ptr, int* __restrict__ cursor,
                       int* __restrict__ eid, int2* __restrict__ edata) {
    int e = blockIdx.x * blockDim.x + threadIdx.x;
    if (e >= N_EDGES) return;
    int d = dst[e];
    int p = row_ptr[d] + atomicAdd(&cursor[d], 1);
    eid[p]   = e;
    edata[p] = make_int2(src[e], __float_as_int(attr[e]));
}

// wave-wide bitonic sort per node by eid: restores np.add.at ascending order
__global__ __launch_bounds__(256) void k_bsort(const int* __restrict__ row_ptr,
                                               int* __restrict__ eid,
                                               int2* __restrict__ edata) {
    int node = blockIdx.x * 4 + (threadIdx.x >> 6);
    int l = threadIdx.x & 63;
    int beg = row_ptr[node], end = row_ptr[node + 1], cnt = end - beg;
    if (cnt <= 1) return;
    if (cnt <= 64) {
        int key = 0x7FFFFFFF, sv = 0, av = 0;
        if (l < cnt) { key = eid[beg + l]; int2 d = edata[beg + l]; sv = d.x; av = d.y; }
        #pragma unroll
        for (int k = 2; k <= 64; k <<= 1) {
            for (int j = k >> 1; j > 0; j >>= 1) {
                int pk = __shfl_xor(key, j);
                int ps = __shfl_xor(sv, j);
                int pa = __shfl_xor(av, j);
                bool lower = (l & j) == 0;
                bool asc   = (l & k) == 0;
                bool take_min = (lower == asc);
                bool take = take_min ? (pk < key) : (pk > key);
                if (take) { key = pk; sv = ps; av = pa; }
            }
        }
        if (l < cnt) { eid[beg + l] = key; edata[beg + l] = make_int2(sv, av); }
    } else if (l == 0) {
        for (int i = beg + 1; i < end; ++i) {
            int ke = eid[i]; int2 kd = edata[i];
            int m = i - 1;
            while (m >= beg && eid[m] > ke) {
                eid[m+1] = eid[m]; edata[m+1] = edata[m]; --m;
            }
            eid[m+1] = ke; edata[m+1] = kd;
        }
    }
}

// ---------- tiled GEMM: 64 nodes x 128 feats per block, fused min/max ----------
__global__ __launch_bounds__(256) void k_gemm(const float* __restrict__ x,
                                              const float* __restrict__ W,
                                              const float* __restrict__ b,
                                              float* __restrict__ h,
                                              unsigned int* __restrict__ mn_e,
                                              unsigned int* __restrict__ mx_e) {
    __shared__ float Ws[32 * 128];
    __shared__ float xs[64 * 36];
    __shared__ float red_mn[8 * 128];
    __shared__ float red_mx[8 * 128];
    const int tid = threadIdx.x;
    const int n0 = blockIdx.x * 64;
    const int jt = tid & 31, nt = tid >> 5;
    const int j0 = jt * 4;

    float acc[8][4];
    #pragma unroll
    for (int a = 0; a < 8; ++a)
        #pragma unroll
        for (int c = 0; c < 4; ++c) acc[a][c] = 0.0f;

    const int ldn = tid >> 2;
    const int kq  = (tid & 3) * 8;
    const int xrow = (n0 + ldn < N_NODES) ? (n0 + ldn) : (N_NODES - 1);
    const float* xg = x + (size_t)xrow * IN_DIM;

    for (int kc = 0; kc < IN_DIM; kc += 32) {
        __syncthreads();
        float4 xa = *(const float4*)(xg + kc + kq);
        float4 xb = *(const float4*)(xg + kc + kq + 4);
        *(float4*)&xs[ldn * 36 + kq]     = xa;
        *(float4*)&xs[ldn * 36 + kq + 4] = xb;
        #pragma unroll
        for (int p = 0; p < 4; ++p) {
            int r = nt + p * 8;
            *(float4*)&Ws[r * 128 + j0] =
                *(const float4*)(W + (size_t)(kc + r) * HID + j0);
        }
        __syncthreads();
        const float* xbase = &xs[nt * 8 * 36];
        #pragma unroll 4
        for (int k = 0; k < 32; ++k) {
            float4 wf = *(const float4*)&Ws[k * 128 + j0];
            #pragma unroll
            for (int ni = 0; ni < 8; ++ni) {
                float xv = xbase[ni * 36 + k];
                acc[ni][0] = __fmaf_rn(xv, wf.x, acc[ni][0]);
                acc[ni][1] = __fmaf_rn(xv, wf.y, acc[ni][1]);
                acc[ni][2] = __fmaf_rn(xv, wf.z, acc[ni][2]);
                acc[ni][3] = __fmaf_rn(xv, wf.w, acc[ni][3]);
            }
        }
    }

    float4 bv = *(const float4*)(b + j0);
    float lmn[4], lmx[4];
    #pragma unroll
    for (int c = 0; c < 4; ++c) { lmn[c] = INFINITY; lmx[c] = -INFINITY; }
    #pragma unroll
    for (int ni = 0; ni < 8; ++ni) {
        acc[ni][0] = __fadd_rn(acc[ni][0], bv.x);
        acc[ni][1] = __fadd_rn(acc[ni][1], bv.y);
        acc[ni][2] = __fadd_rn(acc[ni][2], bv.z);
        acc[ni][3] = __fadd_rn(acc[ni][3], bv.w);
        #pragma unroll
        for (int c = 0; c < 4; ++c) {
            lmn[c] = fminf(lmn[c], acc[ni][c]);
            lmx[c] = fmaxf(lmx[c], acc[ni][c]);
        }
    }
    #pragma unroll
    for (int c = 0; c < 4; ++c) {
        red_mn[nt * 128 + j0 + c] = lmn[c];
        red_mx[nt * 128 + j0 + c] = lmx[c];
    }
    __syncthreads();
    if (tid < 128) {
        float mnv = red_mn[tid], mxv = red_mx[tid];
        #pragma unroll
        for (int r = 1; r < 8; ++r) {
            mnv = fminf(mnv, red_mn[r * 128 + tid]);
            mxv = fmaxf(mxv, red_mx[r * 128 + tid]);
        }
        atomicMin(&mn_e[tid], enc_f(mnv));
        atomicMax(&mx_e[tid], enc_f(mxv));
    }
    #pragma unroll
    for (int ni = 0; ni < 8; ++ni) {
        int n = n0 + nt * 8 + ni;
        if (n < N_NODES)
            *(float4*)&h[(size_t)n * HID + j0] =
                make_float4(acc[ni][0], acc[ni][1], acc[ni][2], acc[ni][3]);
    }
}

// ---------- init spike bitmask ----------
__global__ void k_init_bits(const int* __restrict__ spike_node, uint32_t* __restrict__ sb) {
    int n = blockIdx.x * blockDim.x + threadIdx.x;
    if (n >= N_NODES) return;
    uint32_t f = spike_node[n] ? 0xFFFFFFFFu : 0u;
    sb[(size_t)n * 4 + 0] = f;
    sb[(size_t)n * 4 + 1] = f;
    sb[(size_t)n * 4 + 2] = f;
    sb[(size_t)n * 4 + 3] = f;
}

// ---------- two-level padded device barrier ----------
// leafs: 8 counters, each on its own 256B line; gens likewise; root separate.
// Avoids R6's bug: cnt and gen shared one line -> poll traffic contended
// with arrival RMWs at the LLC.
static __device__ __forceinline__ void gbar2(int* bar, int nblk) {
    __syncthreads();                        // drains each wave's stores (vmcnt 0)
    if (threadIdx.x == 0) {
        __threadfence();                    // release
        const int l   = blockIdx.x & 7;
        const int lsz = (nblk - l + 7) >> 3;
        int* lc = bar + l * 64;             // leaf counter line
        int* lg = bar + 512 + l * 64;       // leaf gen line
        int* rc = bar + 1024;               // root counter line
        int* rg = bar + 1088;               // root gen line
        int gl = __hip_atomic_load(lg, __ATOMIC_RELAXED, __HIP_MEMORY_SCOPE_AGENT);
        int a  = __hip_atomic_fetch_add(lc, 1, __ATOMIC_ACQ_REL, __HIP_MEMORY_SCOPE_AGENT);
        if (a == lsz - 1) {                 // leaf representative
            __hip_atomic_store(lc, 0, __ATOMIC_RELAXED, __HIP_MEMORY_SCOPE_AGENT);
            int gr = __hip_atomic_load(rg, __ATOMIC_RELAXED, __HIP_MEMORY_SCOPE_AGENT);
            int r  = __hip_atomic_fetch_add(rc, 1, __ATOMIC_ACQ_REL, __HIP_MEMORY_SCOPE_AGENT);
            if (r == 7) {
                __hip_atomic_store(rc, 0, __ATOMIC_RELAXED, __HIP_MEMORY_SCOPE_AGENT);
                __hip_atomic_fetch_add(rg, 1, __ATOMIC_ACQ_REL, __HIP_MEMORY_SCOPE_AGENT);
            } else {
                while (__hip_atomic_load(rg, __ATOMIC_RELAXED,
                                         __HIP_MEMORY_SCOPE_AGENT) == gr)
                    __builtin_amdgcn_s_sleep(4);
            }
            __hip_atomic_fetch_add(lg, 1, __ATOMIC_ACQ_REL, __HIP_MEMORY_SCOPE_AGENT);
        } else {
            while (__hip_atomic_load(lg, __ATOMIC_RELAXED,
                                     __HIP_MEMORY_SCOPE_AGENT) == gl)
                __builtin_amdgcn_s_sleep(8);
        }
        __threadfence();                    // acquire
    }
    __syncthreads();
}

// ---------- persistent fused 8-step LIF (templated variants) ----------
// Variant A: NPB=66, 758 blocks, 3 blocks/CU (12 waves/CU latency hiding),
//            unpacked LDS (2x ds_read_b32 per edge), LDS ~38 KB.
// Variant B: NPB=98, 511 blocks, 2 blocks/CU (R6-proven residency shape),
//            PACKED (attr,word) uint2 LDS -> 1x ds_read_b64 per edge, ~78 KB.
// Launched only if the occupancy API proves co-residency; else k_step chain.
// Slot state arrays MUST stay fully unrolled (R4 errata: dynamic indexing
// demotes them to scratch -> 420 MB spill traffic).
template<int TNPB, int TNSLOT, int TECAP, int TPACK, int TMINW>
__global__ __launch_bounds__(256, TMINW) void k_lif_t(
    const int* __restrict__ row_ptr,
    const int2* __restrict__ edata,
    uint32_t* __restrict__ sbA,
    uint32_t* __restrict__ sbB,
    const float* __restrict__ h_raw,
    const unsigned int* __restrict__ mn_e,
    const unsigned int* __restrict__ mx_e,
    float* __restrict__ out,
    int* __restrict__ bar,
    int nblk)
{
    __shared__ int      lrp[TNPB + 1];
    __shared__ int      ed_src_l[TECAP];
    __shared__ float    ed_attr_l[TECAP];
    __shared__ uint32_t ed_wds[TPACK ? 1 : TECAP * 4];      // unpacked words
    __shared__ uint2    ed_pk[TPACK ? TECAP * 4 : 1];       // packed (attr,word)
    __shared__ uint32_t sbw[TNPB][4];

    const int tid = threadIdx.x;
    const int g   = tid >> 5;                 // node group 0..7
    const int ln  = tid & 31;                 // features 4ln..4ln+3
    const int n0  = blockIdx.x * TNPB;
    const int ncnt = min(TNPB, N_NODES - n0);
    const int w = ln >> 3, shb = (ln & 7) * 4;
    const size_t NH = (size_t)N_NODES * HID;

    if (tid <= ncnt) lrp[tid] = row_ptr[n0 + tid];
    __syncthreads();
    const int ebase = lrp[0];
    const int etot  = lrp[ncnt] - ebase;
    const bool inlds = (etot <= TECAP);
    if (inlds) {
        for (int i = tid; i < etot; i += 256) {
            int2 d = edata[ebase + i];
            ed_src_l[i]  = d.x;
            ed_attr_l[i] = __int_as_float(d.y);
        }
    }

    // per-lane normalization constants
    uint4 mnu = *(const uint4*)&mn_e[ln * 4];
    uint4 mxu = *(const uint4*)&mx_e[ln * 4];
    float mn0 = dec_f(mnu.x), mn1 = dec_f(mnu.y), mn2 = dec_f(mnu.z), mn3 = dec_f(mnu.w);
    float dd0 = __fadd_rn(__fsub_rn(dec_f(mxu.x), mn0), 1e-6f);
    float dd1 = __fadd_rn(__fsub_rn(dec_f(mxu.y), mn1), 1e-6f);
    float dd2 = __fadd_rn(__fsub_rn(dec_f(mxu.z), mn2), 1e-6f);
    float dd3 = __fadd_rn(__fsub_rn(dec_f(mxu.w), mn3), 1e-6f);

    // load + normalize h; init v, ref (registers, fully static indexing)
    float4 hs[TNSLOT], vs[TNSLOT];
    uint32_t rcs[TNSLOT];
    #pragma unroll
    for (int s = 0; s < TNSLOT; ++s) {
        hs[s] = make_float4(0.f, 0.f, 0.f, 0.f);
        vs[s] = make_float4(0.f, 0.f, 0.f, 0.f);
        rcs[s] = 0u;
        int m = s * 8 + g;
        if (m < ncnt) {
            size_t idx = (size_t)(n0 + m) * HID + ln * 4;
            float4 t = *(const float4*)&h_raw[idx];
            t.x = __fdiv_rn(__fsub_rn(t.x, mn0), dd0);
            t.y = __fdiv_rn(__fsub_rn(t.y, mn1), dd1);
            t.z = __fdiv_rn(__fsub_rn(t.z, mn2), dd2);
            t.w = __fdiv_rn(__fsub_rn(t.w, mn3), dd3);
            hs[s] = t;
        }
    }
    for (int i = tid; i < ncnt * 4; i += 256) ((uint32_t*)sbw)[i] = 0u;
    __syncthreads();

    for (int t = 0; t < T_STEPS; ++t) {
        const uint32_t* cur = (t & 1) ? sbB : sbA;
        uint32_t*       nxt = (t & 1) ? sbA : sbB;
        if (t > 0) gbar2(bar, nblk);          // step t-1 masks visible everywhere

        if (inlds) {                          // stage this step's spike words
            for (int i = tid; i < etot; i += 256) {
                uint4 wv = *(const uint4*)&cur[(size_t)ed_src_l[i] * 4];
                if (TPACK) {
                    uint32_t ab = __float_as_uint(ed_attr_l[i]);
                    ed_pk[i * 4 + 0] = make_uint2(ab, wv.x);
                    ed_pk[i * 4 + 1] = make_uint2(ab, wv.y);
                    ed_pk[i * 4 + 2] = make_uint2(ab, wv.z);
                    ed_pk[i * 4 + 3] = make_uint2(ab, wv.w);
                } else {
                    *(uint4*)&ed_wds[i * 4] = wv;
                }
            }
        }
        __syncthreads();

        #pragma unroll
        for (int s = 0; s < TNSLOT; ++s) {
            int m = s * 8 + g;
            if (m < ncnt) {
                float ag0 = 0.f, ag1 = 0.f, ag2 = 0.f, ag3 = 0.f;
                if (inlds) {
                    int lb = lrp[m] - ebase, le = lrp[m + 1] - ebase;
                    for (int i = lb; i < le; ++i) {       // ascending edge order
                        uint32_t u; float a;
                        if (TPACK) {
                            uint2 p = ed_pk[i * 4 + w];   // one ds_read_b64
                            a = __uint_as_float(p.x);
                            u = p.y;
                        } else {
                            u = ed_wds[i * 4 + w];
                            a = ed_attr_l[i];
                        }
                        uint32_t bits = (u >> shb) & 0xFu;
                        ag0 = __fadd_rn(ag0, (bits & 1u) ? a : 0.f);   // +0.0 exact
                        ag1 = __fadd_rn(ag1, (bits & 2u) ? a : 0.f);
                        ag2 = __fadd_rn(ag2, (bits & 4u) ? a : 0.f);
                        ag3 = __fadd_rn(ag3, (bits & 8u) ? a : 0.f);
                    }
                } else {                                  // overflow fallback
                    int lb = lrp[m], le = lrp[m + 1];
                    for (int i = lb; i < le; ++i) {
                        int2 d = edata[i];
                        uint32_t u = cur[(size_t)d.x * 4 + w];
                        float a = __int_as_float(d.y);
                        uint32_t bits = (u >> shb) & 0xFu;
                        ag0 = __fadd_rn(ag0, (bits & 1u) ? a : 0.f);
                        ag1 = __fadd_rn(ag1, (bits & 2u) ? a : 0.f);
                        ag2 = __fadd_rn(ag2, (bits & 4u) ? a : 0.f);
                        ag3 = __fadd_rn(ag3, (bits & 8u) ? a : 0.f);
                    }
                }

                // LIF update (identical FP sequence to reference)
                float hv[4] = {hs[s].x, hs[s].y, hs[s].z, hs[s].w};
                float vv[4] = {vs[s].x, vs[s].y, vs[s].z, vs[s].w};
                float ag[4] = {ag0, ag1, ag2, ag3};
                float vf[4], sf[4];
                uint32_t rcu = rcs[s], rcn = 0u, nib = 0u;
                #pragma unroll
                for (int q = 0; q < 4; ++q) {
                    float vn = __fadd_rn(__fadd_rn(__fmul_rn(0.8f, vv[q]), hv[q]), ag[q]);
                    uint32_t rc = (rcu >> (8 * q)) & 0xFFu;
                    bool spk = (vn >= 0.5f) && (rc == 0u);
                    vf[q] = spk ? 0.0f : vn;
                    sf[q] = spk ? 1.0f : 0.0f;
                    uint32_t rnew = spk ? 2u : (rc > 0u ? rc - 1u : 0u);
                    rcn |= rnew << (8 * q);
                    nib |= (spk ? 1u : 0u) << q;
                }
                vs[s] = make_float4(vf[0], vf[1], vf[2], vf[3]);
                rcs[s] = rcn;
                size_t idx = (size_t)(n0 + m) * HID + ln * 4;
                *(float4*)&out[NH + (size_t)t * NH + idx] =
                    make_float4(sf[0], sf[1], sf[2], sf[3]);
                if (t == T_STEPS - 1) {
                    *(float4*)&out[idx] = make_float4(
                        __fadd_rn(hv[0], __fmul_rn(0.5f, vf[0])),
                        __fadd_rn(hv[1], __fmul_rn(0.5f, vf[1])),
                        __fadd_rn(hv[2], __fmul_rn(0.5f, vf[2])),
                        __fadd_rn(hv[3], __fmul_rn(0.5f, vf[3])));
                }
                atomicOr(&sbw[m][w], nib << shb);
            }
        }
        __syncthreads();
        for (int i = tid; i < ncnt * 4; i += 256) {   // publish + re-zero
            nxt[(size_t)n0 * 4 + i] = ((uint32_t*)sbw)[i];
            ((uint32_t*)sbw)[i] = 0u;
        }
    }
}

// ---------- multi-kernel fallback step (R2-verified structure, edata form) ----------
__global__ __launch_bounds__(128) void k_step(const int* __restrict__ row_ptr,
                                              const int2* __restrict__ edata,
                                              const uint32_t* __restrict__ sb_cur,
                                              uint32_t* __restrict__ sb_nxt,
                                              float* __restrict__ h,
                                              float* __restrict__ v,
                                              unsigned char* __restrict__ refc,
                                              const unsigned int* __restrict__ mn_e,
                                              const unsigned int* __restrict__ mx_e,
                                              float* __restrict__ out_spk,
                                              float* __restrict__ out_fus,
                                              int t0, int is_last) {
    __shared__ float    attr_l[4][128];
    __shared__ uint32_t words_l[4][128][4];
    __shared__ uint32_t sbw[16];
    __shared__ int      rp[5];

    const int tid = threadIdx.x;
    const int ns = tid >> 5, ln = tid & 31;
    const int nb = blockIdx.x * 4;
    const int n  = nb + ns;

    if (tid < 16) sbw[tid] = 0;
    if (tid < 5)  rp[tid] = row_ptr[nb + tid];
    __syncthreads();

    const int beg = rp[ns], cnt = rp[ns + 1] - beg;
    int cmax = 0;
    #pragma unroll
    for (int q = 0; q < 4; ++q) cmax = max(cmax, rp[q + 1] - rp[q]);
    const int nchunk = (cmax + 127) >> 7;

    float agg0 = 0.f, agg1 = 0.f, agg2 = 0.f, agg3 = 0.f;
    const int w = ln >> 3, shb = (ln & 7) * 4;

    for (int ch = 0; ch < nchunk; ++ch) {
        int base = ch << 7;
        __syncthreads();
        #pragma unroll
        for (int rep = 0; rep < 4; ++rep) {
            int i = base + rep * 32 + ln;
            if (i < cnt) {
                int2 d = edata[beg + i];
                attr_l[ns][rep * 32 + ln] = __int_as_float(d.y);
                *(uint4*)&words_l[ns][rep * 32 + ln][0] =
                    *(const uint4*)&sb_cur[(size_t)d.x * 4];
            }
        }
        __syncthreads();
        int lim = min(128, cnt - base);
        for (int i = 0; i < lim; ++i) {
            uint32_t u = words_l[ns][i][w];
            float a = attr_l[ns][i];
            uint32_t bits = (u >> shb) & 0xFu;
            agg0 = __fadd_rn(agg0, (bits & 1u) ? a : 0.0f);
            agg1 = __fadd_rn(agg1, (bits & 2u) ? a : 0.0f);
            agg2 = __fadd_rn(agg2, (bits & 4u) ? a : 0.0f);
            agg3 = __fadd_rn(agg3, (bits & 8u) ? a : 0.0f);
        }
    }

    const size_t idx = (size_t)n * HID + ln * 4;
    float4 h4 = *(const float4*)&h[idx];
    if (t0) {
        const int jb = ln * 4;
        float hq[4] = {h4.x, h4.y, h4.z, h4.w};
        #pragma unroll
        for (int q = 0; q < 4; ++q) {
            float mn = dec_f(mn_e[jb + q]);
            float mx = dec_f(mx_e[jb + q]);
            float d2 = __fadd_rn(__fsub_rn(mx, mn), 1e-6f);
            hq[q] = __fdiv_rn(__fsub_rn(hq[q], mn), d2);
        }
        h4 = make_float4(hq[0], hq[1], hq[2], hq[3]);
        *(float4*)&h[idx] = h4;
    }
    float4 v4;
    unsigned int rcu;
    if (t0) { v4 = make_float4(0.f, 0.f, 0.f, 0.f); rcu = 0u; }
    else    { v4 = *(const float4*)&v[idx]; rcu = *(const unsigned int*)&refc[idx]; }

    float hv[4]  = {h4.x, h4.y, h4.z, h4.w};
    float vv[4]  = {v4.x, v4.y, v4.z, v4.w};
    float ag[4]  = {agg0, agg1, agg2, agg3};
    float vf[4], sf[4];
    unsigned int rcn = 0u, nib = 0u;
    #pragma unroll
    for (int q = 0; q < 4; ++q) {
        float vn = __fadd_rn(__fadd_rn(__fmul_rn(0.8f, vv[q]), hv[q]), ag[q]);
        unsigned int rc = (rcu >> (8 * q)) & 0xFFu;
        bool spk = (vn >= 0.5f) && (rc == 0u);
        vf[q] = spk ? 0.0f : vn;
        sf[q] = spk ? 1.0f : 0.0f;
        unsigned int rnew = spk ? 2u : (rc > 0u ? rc - 1u : 0u);
        rcn |= rnew << (8 * q);
        nib |= (spk ? 1u : 0u) << q;
    }
    *(float4*)&v[idx] = make_float4(vf[0], vf[1], vf[2], vf[3]);
    *(unsigned int*)&refc[idx] = rcn;
    *(float4*)&out_spk[idx] = make_float4(sf[0], sf[1], sf[2], sf[3]);
    if (is_last) {
        *(float4*)&out_fus[idx] = make_float4(
            __fadd_rn(hv[0], __fmul_rn(0.5f, vf[0])),
            __fadd_rn(hv[1], __fmul_rn(0.5f, vf[1])),
            __fadd_rn(hv[2], __fmul_rn(0.5f, vf[2])),
            __fadd_rn(hv[3], __fmul_rn(0.5f, vf[3])));
    }
    atomicOr(&sbw[ns * 4 + w], nib << shb);
    __syncthreads();
    if (tid < 16)
        sb_nxt[(size_t)(nb + (tid >> 2)) * 4 + (tid & 3)] = sbw[tid];
}

extern "C" void kernel_launch(void* const* d_in, const int* in_sizes, int n_in,
                              void* d_out, int out_size, void* d_ws, size_t ws_size,
                              hipStream_t stream) {
    const float* x          = (const float*)d_in[0];
    const int*   spike_node = (const int*)  d_in[1];
    const int*   edge_index = (const int*)  d_in[2];   // [2][E]
    const float* edge_attr  = (const float*)d_in[4];
    const float* W          = (const float*)d_in[5];
    const float* b          = (const float*)d_in[6];
    float* out = (float*)d_out;

    const int* src = edge_index;
    const int* dst = edge_index + N_EDGES;

    char* wsp = (char*)d_ws;
    auto alloc = [&](size_t bytes) {
        char* p = wsp;
        wsp += (bytes + 255) & ~(size_t)255;
        return p;
    };
    float*         h        = (float*)        alloc((size_t)N_NODES * HID * 4);
    float*         v        = (float*)        alloc((size_t)N_NODES * HID * 4);
    unsigned char* refc     = (unsigned char*)alloc((size_t)N_NODES * HID);
    uint32_t*      sbA      = (uint32_t*)     alloc((size_t)N_NODES * 16);
    uint32_t*      sbB      = (uint32_t*)     alloc((size_t)N_NODES * 16);
    int*           counts   = (int*)          alloc((size_t)N_NODES * 4);
    int*           cursor   = (int*)          alloc((size_t)N_NODES * 4);
    int*           row_tmp  = (int*)          alloc((size_t)N_NODES * 4);
    int*           row_ptr  = (int*)          alloc((size_t)(N_NODES + 1) * 4);
    int*           blocksum = (int*)          alloc(256 * 4);
    int*           blockoff = (int*)          alloc(256 * 4);
    int*           eid      = (int*)          alloc((size_t)N_EDGES * 4);
    int2*          edata    = (int2*)         alloc((size_t)N_EDGES * 8);
    unsigned int*  mn_e     = (unsigned int*) alloc(HID * 4);
    unsigned int*  mx_e     = (unsigned int*) alloc(HID * 4);
    int*           barv     = (int*)          alloc(8192);

    hipMemsetAsync(counts, 0x00, (size_t)N_NODES * 4, stream);
    hipMemsetAsync(cursor, 0x00, (size_t)N_NODES * 4, stream);
    hipMemsetAsync(mn_e,   0xFF, HID * 4, stream);
    hipMemsetAsync(mx_e,   0x00, HID * 4, stream);
    hipMemsetAsync(barv,   0x00, 8192, stream);

    const int NB = (N_NODES + 255) / 256;   // 196
    const int EB = (N_EDGES + 255) / 256;

    k_count<<<EB, 256, 0, stream>>>(dst, counts);
    k_scan1<<<NB, 256, 0, stream>>>(counts, row_tmp, blocksum);
    k_scan2<<<1, 64, 0, stream>>>(blocksum, blockoff, NB, row_ptr);
    k_scan3<<<NB, 256, 0, stream>>>(row_tmp, blockoff, row_ptr);
    k_fill<<<EB, 256, 0, stream>>>(dst, src, edge_attr, row_ptr, cursor, eid, edata);
    k_bsort<<<N_NODES / 4, 256, 0, stream>>>(row_ptr, eid, edata);

    k_gemm<<<(N_NODES + 63) / 64, 256, 0, stream>>>(x, W, b, h, mn_e, mx_e);
    k_init_bits<<<NB, 256, 0, stream>>>(spike_node, sbA);

    const size_t NH = (size_t)N_NODES * HID;

    // variant A: 66 nodes/block, 758 blocks, needs 3 blocks/CU
    auto kA = k_lif_t<66, 9, 1536, 0, 3>;
    // variant B: 98 nodes/block, 511 blocks, needs 2 blocks/CU (R6-proven shape)
    auto kB = k_lif_t<98, 13, 1920, 1, 2>;
    int occA = 0, occB = 0;
    hipOccupancyMaxActiveBlocksPerMultiprocessor(&occA, kA, 256, 0);
    hipOccupancyMaxActiveBlocksPerMultiprocessor(&occB, kB, 256, 0);

    if (occA >= 3) {
        const int grid = (N_NODES + 65) / 66;          // 758 <= 768
        kA<<<grid, 256, 0, stream>>>(row_ptr, edata, sbA, sbB, h, mn_e, mx_e,
                                     out, barv, grid);
    } else if (occB >= 2) {
        const int grid = (N_NODES + 97) / 98;          // 511 <= 512
        kB<<<grid, 256, 0, stream>>>(row_ptr, edata, sbA, sbB, h, mn_e, mx_e,
                                     out, barv, grid);
    } else {
        for (int t = 0; t < T_STEPS; ++t) {
            uint32_t* cur = (t & 1) ? sbB : sbA;
            uint32_t* nxt = (t & 1) ? sbA : sbB;
            k_step<<<N_NODES / 4, 128, 0, stream>>>(row_ptr, edata, cur, nxt,
                                                    h, v, refc, mn_e, mx_e,
                                                    out + NH + (size_t)t * NH,
                                                    out, (t == 0) ? 1 : 0,
                                                    (t == T_STEPS - 1) ? 1 : 0);
        }
    }
}